// Round 1
// baseline (183.694 us; speedup 1.0000x reference)
//
#include <hip/hip_runtime.h>
#include <hip/hip_bf16.h>

#define R_ 3
#define D_ 7            // 2R+1
#define W_ 49
#define N_ 128
#define K_ 131
#define C_ 21
#define B_ 2
#define NN (N_ * N_)
#define TILE 16
#define PATCH (TILE + 2 * R_)   // 22
#define PSTR 24                  // LDS row stride (uniform 2-way bank access)
#define KC 4                     // k-chunks per tile
#define KCHUNK ((K_ + KC - 1) / KC)  // 33

// Kernel A: per-pixel window softmax over channels, weighted by conv_parameter.
// Aout layout: [B][W][NN], partial-accumulated with atomics across KC chunks.
__global__ __launch_bounds__(256) void rwn_affinity(
    const float* __restrict__ feats,   // [B,K,N,N]
    const int*   __restrict__ mask,    // [B,N,N]
    const float* __restrict__ cp,      // [K]
    float* __restrict__ Aout)          // [B,W,NN] (pre-zeroed)
{
    __shared__ float maskp[PATCH][PSTR];
    __shared__ float patch[PATCH][PSTR];

    const int tile = blockIdx.x;           // 0..63 (8x8 tiles)
    const int kc   = blockIdx.y;           // 0..KC-1
    const int b    = blockIdx.z;           // 0..B-1
    const int ti0 = (tile >> 3) * TILE;
    const int tj0 = (tile & 7) * TILE;
    const int tid = threadIdx.x;
    const int ti = tid >> 4;               // 0..15
    const int tj = tid & 15;               // 0..15
    const int gi = ti0 + ti, gj = tj0 + tj;

    // Stage mask patch (as float), zero-padded out of grid.
    for (int e = tid; e < PATCH * PATCH; e += 256) {
        int pr = e / PATCH, pc = e - pr * PATCH;
        int mi = ti0 + pr - R_, mj = tj0 + pc - R_;
        float mv = 0.f;
        if (mi >= 0 && mi < N_ && mj >= 0 && mj < N_)
            mv = (float)mask[b * NN + mi * N_ + mj];
        maskp[pr][pc] = mv;
    }

    // Per-thread window validity bitmask (grid bounds only).
    unsigned long long vmask = 0ull;
    #pragma unroll
    for (int u = 0; u < D_; ++u) {
        #pragma unroll
        for (int v = 0; v < D_; ++v) {
            int ni = gi + u - R_, nj = gj + v - R_;
            if (ni >= 0 && ni < N_ && nj >= 0 && nj < N_)
                vmask |= (1ull << (u * D_ + v));
        }
    }

    float Aacc[W_];
    #pragma unroll
    for (int w = 0; w < W_; ++w) Aacc[w] = 0.f;

    const int k0 = kc * KCHUNK;
    const int k1 = (k0 + KCHUNK < K_) ? (k0 + KCHUNK) : K_;

    __syncthreads();

    for (int k = k0; k < k1; ++k) {
        const float* fbase = feats + (size_t)(b * K_ + k) * NN;
        for (int e = tid; e < PATCH * PATCH; e += 256) {
            int pr = e / PATCH, pc = e - pr * PATCH;
            int mi = ti0 + pr - R_, mj = tj0 + pc - R_;
            float fv = 0.f;
            if (mi >= 0 && mi < N_ && mj >= 0 && mj < N_)
                fv = fbase[mi * N_ + mj];
            patch[pr][pc] = fv * maskp[pr][pc];
        }
        __syncthreads();

        const float c = patch[ti + R_][tj + R_];
        float ex[W_];
        float denom = 0.f;
        #pragma unroll
        for (int u = 0; u < D_; ++u) {
            #pragma unroll
            for (int v = 0; v < D_; ++v) {
                const int w = u * D_ + v;
                float nb = patch[ti + u][tj + v];
                float t = __expf(fabsf(c - nb));
                t = ((vmask >> w) & 1ull) ? t : 0.f;
                ex[w] = t;
                denom += t;
            }
        }
        const float scale = cp[k] / denom;   // denom >= 1 (center always valid)
        #pragma unroll
        for (int w = 0; w < W_; ++w) Aacc[w] += scale * ex[w];
        __syncthreads();
    }

    const float m = maskp[ti + R_][tj + R_];
    if (m != 0.f) {
        const int pix = gi * N_ + gj;
        float* ab = Aout + (size_t)b * W_ * NN + pix;
        #pragma unroll
        for (int w = 0; w < W_; ++w)
            atomicAdd(ab + w * NN, Aacc[w]);
    }
}

// Kernel B: out[b,q,c] = sum_w A[b,w,p] * x2[b,c,p],  p = q - (u,v), w=(u+3)*7+(v+3)
__global__ __launch_bounds__(256) void rwn_gather(
    const float* __restrict__ Aarr,  // [B,W,NN]
    const float* __restrict__ x2,    // [B,C,NN]
    float* __restrict__ out)         // [B,NN,C]
{
    const int t = blockIdx.x * 256 + threadIdx.x;
    if (t >= B_ * C_ * NN) return;
    const int q  = t & (NN - 1);
    const int bc = t >> 14;
    const int b  = bc / C_;
    const int c  = bc - b * C_;
    const int i = q >> 7, j = q & (N_ - 1);

    const float* Ab = Aarr + (size_t)b * W_ * NN;
    const float* xb = x2 + (size_t)(b * C_ + c) * NN;

    float acc = 0.f;
    #pragma unroll
    for (int u = -R_; u <= R_; ++u) {
        #pragma unroll
        for (int v = -R_; v <= R_; ++v) {
            const int w = (u + R_) * D_ + (v + R_);
            const int pi = i - u, pj = j - v;
            if (pi >= 0 && pi < N_ && pj >= 0 && pj < N_) {
                const int p = pi * N_ + pj;
                acc += Ab[w * NN + p] * xb[p];
            }
        }
    }
    out[(size_t)(b * NN + q) * C_ + c] = acc;
}

extern "C" void kernel_launch(void* const* d_in, const int* in_sizes, int n_in,
                              void* d_out, int out_size, void* d_ws, size_t ws_size,
                              hipStream_t stream) {
    const float* feats = (const float*)d_in[0];   // [B,K,N,N]
    const float* x2    = (const float*)d_in[1];   // [B,C,NN]
    const int*   mask  = (const int*)d_in[2];     // [B,N,N]
    const float* cp    = (const float*)d_in[3];   // [K]
    float* out = (float*)d_out;

    float* Aarr = (float*)d_ws;                   // [B,W,NN] fp32
    const size_t Abytes = (size_t)B_ * W_ * NN * sizeof(float);

    hipMemsetAsync(Aarr, 0, Abytes, stream);

    dim3 gridA(64, KC, B_);
    rwn_affinity<<<gridA, 256, 0, stream>>>(feats, mask, cp, Aarr);

    const int total = B_ * C_ * NN;
    rwn_gather<<<(total + 255) / 256, 256, 0, stream>>>(Aarr, x2, out);
}

// Round 2
// 167.525 us; speedup vs baseline: 1.0965x; 1.0965x over previous
//
#include <hip/hip_runtime.h>
#include <hip/hip_bf16.h>

#define R_ 3
#define D_ 7            // 2R+1
#define W_ 49
#define N_ 128
#define K_ 131
#define C_ 21
#define B_ 2
#define NN (N_ * N_)
#define TILE 16
#define PATCH (TILE + 2 * R_)   // 22
#define PSTR 24                  // LDS row stride: 4x16 read footprint -> exact 2-way (free)
#define KC 8                     // k-chunks per tile
#define KCHUNK ((K_ + KC - 1) / KC)  // 17

// Kernel A: per-pixel window softmax over channels, weighted by conv_parameter.
// Aout layout: [B][W][NN], partial-accumulated with atomics across KC chunks.
__global__ __launch_bounds__(256) void rwn_affinity(
    const float* __restrict__ feats,   // [B,K,N,N]
    const int*   __restrict__ mask,    // [B,N,N]
    const float* __restrict__ cp,      // [K]
    float* __restrict__ Aout)          // [B,W,NN] (pre-zeroed)
{
    __shared__ float patch[PATCH][PSTR];
    __shared__ float centm[TILE][TILE + 1];   // center-pixel mask per tile

    const int tile = blockIdx.x;           // 0..63 (8x8 tiles)
    const int kc   = blockIdx.y;           // 0..KC-1
    const int b    = blockIdx.z;           // 0..B-1
    const int ti0 = (tile >> 3) * TILE;
    const int tj0 = (tile & 7) * TILE;
    const int tid = threadIdx.x;
    const int ti = tid >> 4;               // 0..15
    const int tj = tid & 15;               // 0..15
    const int gi = ti0 + ti, gj = tj0 + tj;

    // ---- Hoisted staging setup: each thread owns 2 patch elements ----
    // element e: pr=e/PATCH, pc=e%PATCH; global pixel (ti0+pr-R, tj0+pc-R)
    int   soff[2];      // clamped global offset (within [0,NN))
    float swt[2];       // valid * mask  (0 kills OOB and unselected)
    int   slds[2];      // lds float-offset
    #pragma unroll
    for (int r = 0; r < 2; ++r) {
        int e = tid + r * 256;
        int pr = e / PATCH, pc = e - pr * PATCH;
        int mi = ti0 + pr - R_, mj = tj0 + pc - R_;
        bool valid = (e < PATCH * PATCH) && mi >= 0 && mi < N_ && mj >= 0 && mj < N_;
        int cmi = mi < 0 ? 0 : (mi > N_ - 1 ? N_ - 1 : mi);
        int cmj = mj < 0 ? 0 : (mj > N_ - 1 ? N_ - 1 : mj);
        soff[r] = cmi * N_ + cmj;
        swt[r]  = valid ? (float)mask[b * NN + soff[r]] : 0.f;
        slds[r] = (e < PATCH * PATCH) ? (pr * PSTR + pc) : (PATCH - 1) * PSTR + PATCH; // spare slot
    }
    centm[0][0] = 0.f; // ensure defined
    __syncthreads();
    if (tid < 256) {
        // store center mask for this thread's pixel
        centm[ti][tj] = (float)mask[b * NN + gi * N_ + gj];
    }

    // Per-thread window validity bitmask (grid bounds only).
    unsigned long long vmask = 0ull;
    #pragma unroll
    for (int u = 0; u < D_; ++u) {
        #pragma unroll
        for (int v = 0; v < D_; ++v) {
            int ni = gi + u - R_, nj = gj + v - R_;
            if (ni >= 0 && ni < N_ && nj >= 0 && nj < N_)
                vmask |= (1ull << (u * D_ + v));
        }
    }

    float Aacc[W_];
    #pragma unroll
    for (int w = 0; w < W_; ++w) Aacc[w] = 0.f;

    const int k0 = kc * KCHUNK;
    const int k1 = (k0 + KCHUNK < K_) ? (k0 + KCHUNK) : K_;
    const float* fb = feats + (size_t)b * K_ * NN;

    __syncthreads();

    for (int k = k0; k < k1; ++k) {
        const float* fbase = fb + (size_t)k * NN;
        #pragma unroll
        for (int r = 0; r < 2; ++r) {
            float fv = fbase[soff[r]] * swt[r];
            *((float*)patch + slds[r]) = fv;
        }
        __syncthreads();

        const float c = patch[ti + R_][tj + R_];
        float ex[W_];
        float denom = 0.f;
        #pragma unroll
        for (int u = 0; u < D_; ++u) {
            #pragma unroll
            for (int v = 0; v < D_; ++v) {
                const int w = u * D_ + v;
                float nb = patch[ti + u][tj + v];
                float t = __expf(fabsf(c - nb));
                t = ((vmask >> w) & 1ull) ? t : 0.f;
                ex[w] = t;
                denom += t;
            }
        }
        const float scale = cp[k] * __frcp_rn(denom);   // denom >= 1 (center always valid)
        #pragma unroll
        for (int w = 0; w < W_; ++w) Aacc[w] += scale * ex[w];
        __syncthreads();
    }

    if (centm[ti][tj] != 0.f) {
        const int pix = gi * N_ + gj;
        float* ab = Aout + (size_t)b * W_ * NN + pix;
        #pragma unroll
        for (int w = 0; w < W_; ++w)
            atomicAdd(ab + w * NN, Aacc[w]);
    }
}

// Kernel B: out[b,q,c] = sum_w A[b,w,p] * x2[b,c,p],  p = q - (u,v), w=(u+3)*7+(v+3)
// Branchless: clamp address, multiply by 0/1 validity.
__global__ __launch_bounds__(256) void rwn_gather(
    const float* __restrict__ Aarr,  // [B,W,NN]
    const float* __restrict__ x2,    // [B,C,NN]
    float* __restrict__ out)         // [B,NN,C]
{
    const int t = blockIdx.x * 256 + threadIdx.x;
    if (t >= B_ * C_ * NN) return;
    const int q  = t & (NN - 1);
    const int bc = t >> 14;
    const int b  = bc / C_;
    const int c  = bc - b * C_;
    const int i = q >> 7, j = q & (N_ - 1);

    const float* Ab = Aarr + (size_t)b * W_ * NN;
    const float* xb = x2 + (size_t)(b * C_ + c) * NN;

    float acc = 0.f;
    #pragma unroll
    for (int u = -R_; u <= R_; ++u) {
        const int pi = i - u;
        const int cpi = pi < 0 ? 0 : (pi > N_ - 1 ? N_ - 1 : pi);
        const float rowv = (pi >= 0 && pi < N_) ? 1.f : 0.f;
        #pragma unroll
        for (int v = -R_; v <= R_; ++v) {
            const int w = (u + R_) * D_ + (v + R_);
            const int pj = j - v;
            const int cpj = pj < 0 ? 0 : (pj > N_ - 1 ? N_ - 1 : pj);
            const float vv = (pj >= 0 && pj < N_) ? rowv : 0.f;
            const int p = cpi * N_ + cpj;
            acc += vv * Ab[w * NN + p] * xb[p];
        }
    }
    out[(size_t)(b * NN + q) * C_ + c] = acc;
}

extern "C" void kernel_launch(void* const* d_in, const int* in_sizes, int n_in,
                              void* d_out, int out_size, void* d_ws, size_t ws_size,
                              hipStream_t stream) {
    const float* feats = (const float*)d_in[0];   // [B,K,N,N]
    const float* x2    = (const float*)d_in[1];   // [B,C,NN]
    const int*   mask  = (const int*)d_in[2];     // [B,N,N]
    const float* cp    = (const float*)d_in[3];   // [K]
    float* out = (float*)d_out;

    float* Aarr = (float*)d_ws;                   // [B,W,NN] fp32
    const size_t Abytes = (size_t)B_ * W_ * NN * sizeof(float);

    hipMemsetAsync(Aarr, 0, Abytes, stream);

    dim3 gridA(64, KC, B_);
    rwn_affinity<<<gridA, 256, 0, stream>>>(feats, mask, cp, Aarr);

    const int total = B_ * C_ * NN;
    rwn_gather<<<(total + 255) / 256, 256, 0, stream>>>(Aarr, x2, out);
}